// Round 3
// baseline (261.919 us; speedup 1.0000x reference)
//
#include <hip/hip_runtime.h>
#include <hip/hip_bf16.h>
#include <stdint.h>

// y = x @ W^T + bias ; x:(32,4096) f32, W:(11008,4096) f32, bias:(11008) f32
// HBM-bound on streaming W (180 MB, read exactly once). bf16 MFMA compute.
//
// 688 blocks x 16 output cols, 4 waves split K (1024 each). W streamed
// nontemporal straight to registers in B-fragment layout (two dwordx4 of 8
// contiguous floats per lane), fp32->bf16 RNE in-register, MFMA, cross-wave
// LDS reduce. x (bf16, 256 KB) stays L2-resident since W bypasses cache.

#define M 32
#define N 11008
#define K 4096
#define BN 16
#define WKSLICE (K / 4)          // 1024 k per wave
#define KSTEPS (WKSLICE / 32)    // 32 MFMA k-steps per wave

typedef __attribute__((ext_vector_type(8))) short bf16x8;
typedef __attribute__((ext_vector_type(4))) float f32x4;

// two fp32 -> packed bf16 pair, round-to-nearest-even (finite inputs)
static __device__ __forceinline__ unsigned int pk2bf(float f0, float f1) {
    unsigned int u0 = __float_as_uint(f0);
    unsigned int u1 = __float_as_uint(f1);
    u0 += 0x7fffu + ((u0 >> 16) & 1u);
    u1 += 0x7fffu + ((u1 >> 16) & 1u);
    return (u0 >> 16) | (u1 & 0xffff0000u);
}

// ---------------------------------------------------------------------------
// Kernel 1: x fp32 -> bf16 into ws (32768 uint2 of 4 bf16).
// ---------------------------------------------------------------------------
__global__ __launch_bounds__(256) void cvt_kernel(
    const float* __restrict__ x, unsigned short* __restrict__ xbf)
{
    int i = blockIdx.x * 256 + threadIdx.x;          // 128 blocks x 256 = 32768
    f32x4 v = ((const f32x4*)x)[i];
    uint2 o;
    o.x = pk2bf(v.x, v.y);
    o.y = pk2bf(v.z, v.w);
    ((uint2*)xbf)[i] = o;
}

// ---------------------------------------------------------------------------
// Kernel 2: GEMM, wave-autonomous K-streaming, NT W loads.
// B-frag (16x16x32): lane holds B[k = quad*8 + j][n = l15] = W[nbase+l15][k]
// A-frag: lane holds A[m = l15 (+16)][k = quad*8 + j] from bf16 x.
// C/D: col = lane&15, row = quad*4 + reg.
// ---------------------------------------------------------------------------
__global__ __launch_bounds__(256) void gemm_kernel(
    const float* __restrict__ W, const unsigned short* __restrict__ xbf,
    const float* __restrict__ bias, float* __restrict__ out)
{
    __shared__ float red[4 * 512];   // 4 waves x (32 m x 16 n) fp32 = 8 KB

    const int tid  = threadIdx.x;
    const int wave = tid >> 6;
    const int lane = tid & 63;
    const int quad = lane >> 4;
    const int l15  = lane & 15;

    const int nbase = blockIdx.x * BN;
    const int kw    = wave * WKSLICE;

    const f32x4*  wp  = (const f32x4*)(W + (size_t)(nbase + l15) * K + kw + quad * 8);
    const bf16x8* ap0 = (const bf16x8*)(xbf + (size_t)l15 * K        + kw + quad * 8);
    const bf16x8* ap1 = (const bf16x8*)((const unsigned short*)ap0 + (size_t)16 * K);

    f32x4 acc0 = {0.f, 0.f, 0.f, 0.f};
    f32x4 acc1 = {0.f, 0.f, 0.f, 0.f};

    #pragma unroll 8
    for (int s = 0; s < KSTEPS; ++s) {
        // W: 32 floats ahead per step = 8 f32x4; this lane's two chunks
        f32x4 w0 = __builtin_nontemporal_load(wp + s * 8);
        f32x4 w1 = __builtin_nontemporal_load(wp + s * 8 + 1);
        bf16x8 a0 = ap0[s * 4];      // 32 bf16 per step = 4 bf16x8
        bf16x8 a1 = ap1[s * 4];

        union { bf16x8 v; unsigned int u[4]; } b;
        b.u[0] = pk2bf(w0.x, w0.y);
        b.u[1] = pk2bf(w0.z, w0.w);
        b.u[2] = pk2bf(w1.x, w1.y);
        b.u[3] = pk2bf(w1.z, w1.w);

        acc0 = __builtin_amdgcn_mfma_f32_16x16x32_bf16(a0, b.v, acc0, 0, 0, 0);
        acc1 = __builtin_amdgcn_mfma_f32_16x16x32_bf16(a1, b.v, acc1, 0, 0, 0);
    }

    // partials -> LDS (C/D layout: row = quad*4 + r, col = l15)
    #pragma unroll
    for (int r = 0; r < 4; ++r) {
        red[wave * 512 + (quad * 4 + r) * 16 + l15]      = acc0[r];
        red[wave * 512 + (16 + quad * 4 + r) * 16 + l15] = acc1[r];
    }
    __syncthreads();

    // 512 outputs, 256 threads x 2: sum 4 waves, add bias, store
    for (int e = tid; e < 512; e += 256) {
        float s = red[e] + red[512 + e] + red[1024 + e] + red[1536 + e];
        int m = e >> 4, n = e & 15;
        out[(size_t)m * N + nbase + n] = s + bias[nbase + n];
    }
}

extern "C" void kernel_launch(void* const* d_in, const int* in_sizes, int n_in,
                              void* d_out, int out_size, void* d_ws, size_t ws_size,
                              hipStream_t stream) {
    const float* x    = (const float*)d_in[0];
    const float* W    = (const float*)d_in[1];
    const float* bias = (const float*)d_in[2];
    float* out        = (float*)d_out;
    unsigned short* xbf = (unsigned short*)d_ws;   // 256 KB

    cvt_kernel<<<(M * K / 4) / 256, 256, 0, stream>>>(x, xbf);
    gemm_kernel<<<N / BN, 256, 0, stream>>>(W, xbf, bias, out);
}

// Round 4
// 260.051 us; speedup vs baseline: 1.0072x; 1.0072x over previous
//
#include <hip/hip_runtime.h>
#include <hip/hip_bf16.h>
#include <stdint.h>

// y = x @ W^T + bias ; x:(32,4096) f32, W:(11008,4096) f32, bias:(11008) f32
// HBM-bound on streaming W (180 MB, read exactly once — fp32 restore each
// iter makes this the irreducible floor, ~29 us at 6.3 TB/s). bf16 MFMA.
//
// 688 blocks x 16 output cols, 4 waves split K (1024 each). W streamed
// straight to registers in B-fragment layout (two dwordx4 of 8 contiguous
// floats per lane), fp32->bf16 RNE in-register, MFMA, cross-wave LDS reduce.
// No atomics, no K-loop barriers. NT loads tried in R3: no benefit (noise-
// level regression), reverted to plain cached loads (R2 best: 254.6 us).

#define M 32
#define N 11008
#define K 4096
#define BN 16
#define WKSLICE (K / 4)          // 1024 k per wave
#define KSTEPS (WKSLICE / 32)    // 32 MFMA k-steps per wave

typedef __attribute__((ext_vector_type(8))) short bf16x8;
typedef __attribute__((ext_vector_type(4))) float f32x4;

// two fp32 -> packed bf16 pair, round-to-nearest-even (finite inputs)
static __device__ __forceinline__ unsigned int pk2bf(float f0, float f1) {
    unsigned int u0 = __float_as_uint(f0);
    unsigned int u1 = __float_as_uint(f1);
    u0 += 0x7fffu + ((u0 >> 16) & 1u);
    u1 += 0x7fffu + ((u1 >> 16) & 1u);
    return (u0 >> 16) | (u1 & 0xffff0000u);
}

// ---------------------------------------------------------------------------
// Kernel 1: x fp32 -> bf16 into ws (32768 uint2 of 4 bf16).
// ---------------------------------------------------------------------------
__global__ __launch_bounds__(256) void cvt_kernel(
    const float* __restrict__ x, unsigned short* __restrict__ xbf)
{
    int i = blockIdx.x * 256 + threadIdx.x;          // 128 blocks x 256 = 32768
    f32x4 v = ((const f32x4*)x)[i];
    uint2 o;
    o.x = pk2bf(v.x, v.y);
    o.y = pk2bf(v.z, v.w);
    ((uint2*)xbf)[i] = o;
}

// ---------------------------------------------------------------------------
// Kernel 2: GEMM, wave-autonomous K-streaming.
// B-frag (16x16x32): lane holds B[k = quad*8 + j][n = l15] = W[nbase+l15][k]
// A-frag: lane holds A[m = l15 (+16)][k = quad*8 + j] from bf16 x.
// C/D: col = lane&15, row = quad*4 + reg.
// ---------------------------------------------------------------------------
__global__ __launch_bounds__(256) void gemm_kernel(
    const float* __restrict__ W, const unsigned short* __restrict__ xbf,
    const float* __restrict__ bias, float* __restrict__ out)
{
    __shared__ float red[4 * 512];   // 4 waves x (32 m x 16 n) fp32 = 8 KB

    const int tid  = threadIdx.x;
    const int wave = tid >> 6;
    const int lane = tid & 63;
    const int quad = lane >> 4;
    const int l15  = lane & 15;

    const int nbase = blockIdx.x * BN;
    const int kw    = wave * WKSLICE;

    const f32x4*  wp  = (const f32x4*)(W + (size_t)(nbase + l15) * K + kw + quad * 8);
    const bf16x8* ap0 = (const bf16x8*)(xbf + (size_t)l15 * K        + kw + quad * 8);
    const bf16x8* ap1 = (const bf16x8*)((const unsigned short*)ap0 + (size_t)16 * K);

    f32x4 acc0 = {0.f, 0.f, 0.f, 0.f};
    f32x4 acc1 = {0.f, 0.f, 0.f, 0.f};

    #pragma unroll 8
    for (int s = 0; s < KSTEPS; ++s) {
        f32x4 w0 = wp[s * 8];        // this lane's two 16B chunks of W row
        f32x4 w1 = wp[s * 8 + 1];
        bf16x8 a0 = ap0[s * 4];      // 32 bf16 per step = 4 bf16x8 stride
        bf16x8 a1 = ap1[s * 4];

        union { bf16x8 v; unsigned int u[4]; } b;
        b.u[0] = pk2bf(w0.x, w0.y);
        b.u[1] = pk2bf(w0.z, w0.w);
        b.u[2] = pk2bf(w1.x, w1.y);
        b.u[3] = pk2bf(w1.z, w1.w);

        acc0 = __builtin_amdgcn_mfma_f32_16x16x32_bf16(a0, b.v, acc0, 0, 0, 0);
        acc1 = __builtin_amdgcn_mfma_f32_16x16x32_bf16(a1, b.v, acc1, 0, 0, 0);
    }

    // partials -> LDS (C/D layout: row = quad*4 + r, col = l15)
    #pragma unroll
    for (int r = 0; r < 4; ++r) {
        red[wave * 512 + (quad * 4 + r) * 16 + l15]      = acc0[r];
        red[wave * 512 + (16 + quad * 4 + r) * 16 + l15] = acc1[r];
    }
    __syncthreads();

    // 512 outputs, 256 threads x 2: sum 4 waves, add bias, store
    for (int e = tid; e < 512; e += 256) {
        float s = red[e] + red[512 + e] + red[1024 + e] + red[1536 + e];
        int m = e >> 4, n = e & 15;
        out[(size_t)m * N + nbase + n] = s + bias[nbase + n];
    }
}

extern "C" void kernel_launch(void* const* d_in, const int* in_sizes, int n_in,
                              void* d_out, int out_size, void* d_ws, size_t ws_size,
                              hipStream_t stream) {
    const float* x    = (const float*)d_in[0];
    const float* W    = (const float*)d_in[1];
    const float* bias = (const float*)d_in[2];
    float* out        = (float*)d_out;
    unsigned short* xbf = (unsigned short*)d_ws;   // 256 KB

    cvt_kernel<<<(M * K / 4) / 256, 256, 0, stream>>>(x, xbf);
    gemm_kernel<<<N / BN, 256, 0, stream>>>(W, xbf, bias, out);
}